// Round 7
// baseline (263.106 us; speedup 1.0000x reference)
//
#include <hip/hip_runtime.h>

typedef unsigned short u16;
typedef __attribute__((ext_vector_type(8))) short bf16x8;   // 8 bf16 in 4 VGPRs
typedef __attribute__((ext_vector_type(4))) float f32x4;

#define CST 0.18033688011112042f  // 0.125 * log2(e)

__device__ inline u16 f2bf(float f) {
    unsigned u;
    __builtin_memcpy(&u, &f, 4);
    unsigned r = (u + 0x7FFF + ((u >> 16) & 1)) >> 16;   // RNE
    return (u16)r;
}
__device__ inline unsigned pack2(float lo, float hi) {
    return (unsigned)f2bf(lo) | ((unsigned)f2bf(hi) << 16);
}
__device__ inline unsigned fbits(float f) {
    unsigned u;
    __builtin_memcpy(&u, &f, 4);
    return u;
}
__device__ inline f32x4 fzero() {
    f32x4 z = {0.f, 0.f, 0.f, 0.f};
    return z;
}
__device__ inline f32x4 mfma16(bf16x8 a, bf16x8 b, f32x4 c) {
    return __builtin_amdgcn_mfma_f32_16x16x32_bf16(a, b, c, 0, 0, 0);
}

// ---------------------------------------------------------------------------
// fp32 -> bf16 tiled transpose: out[C][R] (bf16) = in[R][C] (fp32)
// ---------------------------------------------------------------------------
__global__ void transpose_f32_bf16(const float* __restrict__ in,
                                   u16* __restrict__ out, int R, int C) {
    __shared__ float tile[32][33];
    int c0 = blockIdx.x * 32, r0 = blockIdx.y * 32;
    int tx = threadIdx.x, ty = threadIdx.y;  // 32 x 8
#pragma unroll
    for (int j = 0; j < 32; j += 8)
        tile[ty + j][tx] = in[(size_t)(r0 + ty + j) * C + c0 + tx];
    __syncthreads();
#pragma unroll
    for (int j = 0; j < 32; j += 8)
        out[(size_t)(c0 + ty + j) * R + r0 + tx] = f2bf(tile[tx][ty + j]);
}

// ---------------------------------------------------------------------------
// fp32 -> bf16 flat convert (x). 8 elements/thread.
// ---------------------------------------------------------------------------
__global__ __launch_bounds__(256) void cvt_f32_bf16(const float* __restrict__ in,
                                                    u16* __restrict__ out) {
    int i = (blockIdx.x * 256 + threadIdx.x) * 8;
    float4 a = *(const float4*)(in + i);
    float4 b = *(const float4*)(in + i + 4);
    uint4 w;
    w.x = pack2(a.x, a.y);
    w.y = pack2(a.z, a.w);
    w.z = pack2(b.x, b.y);
    w.w = pack2(b.z, b.w);
    *(uint4*)(out + i) = w;
}

// ---------------------------------------------------------------------------
// V pre-transpose with per-32-key permutation.
// qkv [4096][2304] (V at 1536+h*64+dh) -> vt[h*64+dh][key'] where within each
// 32-key group key' = (k&15)*2 + (k>>4).  Tile = 128 keys.
// ---------------------------------------------------------------------------
__global__ __launch_bounds__(256) void vtrans(const u16* __restrict__ qkv,
                                              u16* __restrict__ vt) {
    __shared__ u16 T[64 * 136];  // [dh][key'] padded
    int t = threadIdx.x;
    int h = blockIdx.y, kv0 = blockIdx.x * 128;
    {
        int key = t >> 1, ch = (t & 1) * 32;
        const u16* vp = qkv + (size_t)(kv0 + key) * 2304 + 1536 + h * 64 + ch;
        u16 tmp[32];
        *(uint4*)&tmp[0]  = *(const uint4*)vp;
        *(uint4*)&tmp[8]  = *(const uint4*)(vp + 8);
        *(uint4*)&tmp[16] = *(const uint4*)(vp + 16);
        *(uint4*)&tmp[24] = *(const uint4*)(vp + 24);
        int k5 = key & 31, w = key >> 5;
        int kp = (w << 5) | ((k5 & 15) << 1) | (k5 >> 4);
#pragma unroll
        for (int j = 0; j < 32; j++) T[(ch + j) * 136 + kp] = tmp[j];
    }
    __syncthreads();
    {
        int dh = t >> 2, kc = (t & 3) * 32;
        uint4 o0 = *(const uint4*)&T[dh * 136 + kc];
        uint4 o1 = *(const uint4*)&T[dh * 136 + kc + 8];
        uint4 o2 = *(const uint4*)&T[dh * 136 + kc + 16];
        uint4 o3 = *(const uint4*)&T[dh * 136 + kc + 24];
        u16* op = vt + ((size_t)(h * 64 + dh)) * 4096 + kv0 + kc;
        *(uint4*)op = o0;
        *(uint4*)(op + 8) = o1;
        *(uint4*)(op + 16) = o2;
        *(uint4*)(op + 24) = o3;
    }
}

// ---------------------------------------------------------------------------
// C[M,N] = A[M,K] @ Bt[N,K]^T + bias[N].  A,Bt bf16; bias fp32; C fp32 or bf16.
// SCALE_Q: multiply by CST for cols < 768.  (validated r4-r6)
// ---------------------------------------------------------------------------
#define GLDA 40  // 32 + 8 pad

template <bool OUT_F32, bool SCALE_Q>
__global__ __launch_bounds__(256) void gemm_bt(const u16* __restrict__ A,
                                               const u16* __restrict__ Bt,
                                               const float* __restrict__ bias,
                                               void* __restrict__ Cv,
                                               int M, int N, int K) {
    __shared__ u16 As[128 * GLDA];
    __shared__ u16 Bs[128 * GLDA];

    int t = threadIdx.x;
    int wave = t >> 6, lane = t & 63, quad = lane >> 4, l16 = lane & 15;
    int mbase = blockIdx.y * 128, nbase = blockIdx.x * 128;
    int mw = (wave & 1) * 64, nw = (wave >> 1) * 64;

    f32x4 acc[4][4];
#pragma unroll
    for (int i = 0; i < 4; i++)
#pragma unroll
        for (int j = 0; j < 4; j++) acc[i][j] = fzero();

    int arow = t >> 1, acol = (t & 1) * 16;
    const u16* Ag = A + (size_t)(mbase + arow) * K + acol;
    const u16* Bg = Bt + (size_t)(nbase + arow) * K + acol;
    u16* Asw = &As[arow * GLDA + acol];
    u16* Bsw = &Bs[arow * GLDA + acol];

    for (int kt = 0; kt < K; kt += 32) {
        uint4 a0 = *(const uint4*)(Ag + kt);
        uint4 a1 = *(const uint4*)(Ag + kt + 8);
        uint4 b0 = *(const uint4*)(Bg + kt);
        uint4 b1 = *(const uint4*)(Bg + kt + 8);
        *(uint4*)(Asw) = a0;
        *(uint4*)(Asw + 8) = a1;
        *(uint4*)(Bsw) = b0;
        *(uint4*)(Bsw + 8) = b1;
        __syncthreads();

        bf16x8 af[4], bfr[4];
#pragma unroll
        for (int i = 0; i < 4; i++)
            af[i] = *(const bf16x8*)&As[(mw + i * 16 + l16) * GLDA + quad * 8];
#pragma unroll
        for (int i = 0; i < 4; i++)
            bfr[i] = *(const bf16x8*)&Bs[(nw + i * 16 + l16) * GLDA + quad * 8];
#pragma unroll
        for (int mi = 0; mi < 4; mi++)
#pragma unroll
            for (int ni = 0; ni < 4; ni++)
                acc[mi][ni] = mfma16(af[mi], bfr[ni], acc[mi][ni]);
        __syncthreads();
    }

#pragma unroll
    for (int ni = 0; ni < 4; ni++) {
        int col = nbase + nw + ni * 16 + l16;
        float bv = bias[col];
        float scale = (SCALE_Q && col < 768) ? CST : 1.0f;
#pragma unroll
        for (int mi = 0; mi < 4; mi++) {
#pragma unroll
            for (int r = 0; r < 4; r++) {
                int row = mbase + mw + mi * 16 + quad * 4 + r;
                float v = (acc[mi][ni][r] + bv) * scale;
                if (OUT_F32)
                    ((float*)Cv)[(size_t)row * N + col] = v;
                else
                    ((u16*)Cv)[(size_t)row * N + col] = f2bf(v);
            }
        }
    }
}

// ---------------------------------------------------------------------------
// MFMA flash attention v3: key-split waves.
// Block = 4 waves, 64 q-rows, KV tiles of 128 keys; wave w owns keys
// w*32..w*32+32 of every tile and computes all 64 q-rows (Q in registers).
// Max-free softmax (Q pre-scaled by CST; scores bounded ~|9|), per-wave O/l
// partials merged exactly at the end.  attn out: [4096][768] bf16.
// ---------------------------------------------------------------------------
#define SEQ 4096
#define QKV_LD 2304
#define LK 72    // Ks row stride (64 + 8)
#define LV 136   // VTs row stride (128 + 8)
#define LP 40    // Ps row stride (32 + 8)

__global__ __launch_bounds__(256, 2) void attn_flash(const u16* __restrict__ qkv,
                                                     const u16* __restrict__ vt,
                                                     u16* __restrict__ attn) {
    // manual layout: Ks [128][LK] u16 | VTs [64][LV] u16 | Ps [4][64][LP] u16
    __shared__ __align__(16) char smem[56320];
    u16* Ks  = (u16*)smem;                    // 18432 B
    u16* VTs = (u16*)(smem + 18432);          // 17408 B
    u16* Ps  = (u16*)(smem + 35840);          // 20480 B
    __shared__ float Lm[4][64];

    int t = threadIdx.x;
    int wave = t >> 6, lane = t & 63, quad = lane >> 4, l16 = lane & 15;
    int h = blockIdx.y;
    int q0 = blockIdx.x * 64;
    const int QOFF = h * 64, KOFF = 768 + h * 64;
    u16* Ps_w = Ps + wave * (64 * LP);

    // Q fragments for all 4 q-subtiles (A-layout: row=l16, k=quad*8[+32])
    bf16x8 qf[4][2];
#pragma unroll
    for (int qs = 0; qs < 4; qs++) {
        const u16* qp = qkv + (size_t)(q0 + qs * 16 + l16) * QKV_LD + QOFF + quad * 8;
        qf[qs][0] = *(const bf16x8*)(qp);
        qf[qs][1] = *(const bf16x8*)(qp + 32);
    }

    f32x4 o[4][4];
    float l4[4][4];
#pragma unroll
    for (int qs = 0; qs < 4; qs++)
#pragma unroll
        for (int j = 0; j < 4; j++) {
            o[qs][j] = fzero();
            l4[qs][j] = 0.f;
        }

    // staging coords
    int krow = t >> 1, kch = (t & 1) * 32;    // K: 128 rows x 64 dh
    int vdh = t >> 2, vkc = (t & 3) * 32;     // V^T: 64 rows x 128 keys
    const u16* vsrc = vt + ((size_t)(h * 64 + vdh)) * SEQ + vkc;

    for (int kv0 = 0; kv0 < SEQ; kv0 += 128) {
        // ---- stage K [128][64] and V^T [64][128'] — all b128 ----
        {
            const u16* kp = qkv + (size_t)(kv0 + krow) * QKV_LD + KOFF + kch;
            uint4 k0 = *(const uint4*)kp;
            uint4 k1 = *(const uint4*)(kp + 8);
            uint4 k2 = *(const uint4*)(kp + 16);
            uint4 k3 = *(const uint4*)(kp + 24);
            u16* kd = &Ks[krow * LK + kch];
            *(uint4*)kd = k0;
            *(uint4*)(kd + 8) = k1;
            *(uint4*)(kd + 16) = k2;
            *(uint4*)(kd + 24) = k3;
            const u16* vp = vsrc + kv0;
            uint4 v0 = *(const uint4*)vp;
            uint4 v1 = *(const uint4*)(vp + 8);
            uint4 v2 = *(const uint4*)(vp + 16);
            uint4 v3 = *(const uint4*)(vp + 24);
            u16* vd = &VTs[vdh * LV + vkc];
            *(uint4*)vd = v0;
            *(uint4*)(vd + 8) = v1;
            *(uint4*)(vd + 16) = v2;
            *(uint4*)(vd + 24) = v3;
        }
        __syncthreads();

        // ---- K fragments for this wave's 32 keys (shared across all qs) ----
        bf16x8 kf[2][2];
#pragma unroll
        for (int kt = 0; kt < 2; kt++) {
            const u16* kb = &Ks[(wave * 32 + kt * 16 + l16) * LK + quad * 8];
            kf[kt][0] = *(const bf16x8*)(kb);
            kf[kt][1] = *(const bf16x8*)(kb + 32);
        }
        // ---- V fragments (B-layout rows of V^T), shared across all qs ----
        bf16x8 vf[4];
#pragma unroll
        for (int nt = 0; nt < 4; nt++)
            vf[nt] = *(const bf16x8*)&VTs[(nt * 16 + l16) * LV + wave * 32 + quad * 8];

        // ---- S = Q K^T, softmax, pack P (truncated bf16 via v_perm) ----
#pragma unroll
        for (int qs = 0; qs < 4; qs++) {
            f32x4 s0 = mfma16(qf[qs][0], kf[0][0], fzero());
            s0 = mfma16(qf[qs][1], kf[0][1], s0);
            f32x4 s1 = mfma16(qf[qs][0], kf[1][0], fzero());
            s1 = mfma16(qf[qs][1], kf[1][1], s1);
#pragma unroll
            for (int r = 0; r < 4; r++) {
                float p0 = exp2f(s0[r]);
                float p1 = exp2f(s1[r]);
                l4[qs][r] += p0 + p1;
                unsigned pk = __builtin_amdgcn_perm(fbits(p1), fbits(p0), 0x07060302u);
                *(unsigned*)&Ps_w[(qs * 16 + quad * 4 + r) * LP + l16 * 2] = pk;
            }
        }

        // ---- O += P V over this wave's 32 keys ----
#pragma unroll
        for (int qs = 0; qs < 4; qs++) {
            bf16x8 pf = *(const bf16x8*)&Ps_w[(qs * 16 + l16) * LP + quad * 8];
#pragma unroll
            for (int nt = 0; nt < 4; nt++)
                o[qs][nt] = mfma16(pf, vf[nt], o[qs][nt]);
        }
        __syncthreads();
    }

    // ---- reduce l over the 16 key-lanes (within quad group) ----
#pragma unroll
    for (int qs = 0; qs < 4; qs++)
#pragma unroll
        for (int r = 0; r < 4; r++) {
#pragma unroll
            for (int off = 1; off < 16; off <<= 1)
                l4[qs][r] += __shfl_xor(l4[qs][r], off);
        }
    if (l16 == 0) {
#pragma unroll
        for (int qs = 0; qs < 4; qs++)
#pragma unroll
            for (int r = 0; r < 4; r++)
                Lm[wave][qs * 16 + quad * 4 + r] = l4[qs][r];
    }

    // ---- cross-wave O merge (exact: max-free partials just add) ----
    float* M0 = (float*)smem;              // [64][68]
    float* M1 = M0 + 64 * 68;
    __syncthreads();
    if (wave >= 2) {
        float* M = (wave == 2) ? M0 : M1;
#pragma unroll
        for (int qs = 0; qs < 4; qs++)
#pragma unroll
            for (int nt = 0; nt < 4; nt++)
#pragma unroll
                for (int r = 0; r < 4; r++)
                    M[(qs * 16 + quad * 4 + r) * 68 + nt * 16 + l16] = o[qs][nt][r];
    }
    __syncthreads();
    if (wave < 2) {
        float* M = (wave == 0) ? M0 : M1;
#pragma unroll
        for (int qs = 0; qs < 4; qs++)
#pragma unroll
            for (int nt = 0; nt < 4; nt++)
#pragma unroll
                for (int r = 0; r < 4; r++)
                    o[qs][nt][r] += M[(qs * 16 + quad * 4 + r) * 68 + nt * 16 + l16];
    }
    __syncthreads();
    if (wave == 1) {
#pragma unroll
        for (int qs = 0; qs < 4; qs++)
#pragma unroll
            for (int nt = 0; nt < 4; nt++)
#pragma unroll
                for (int r = 0; r < 4; r++)
                    M0[(qs * 16 + quad * 4 + r) * 68 + nt * 16 + l16] = o[qs][nt][r];
    }
    __syncthreads();
    if (wave == 0) {
#pragma unroll
        for (int qs = 0; qs < 4; qs++) {
#pragma unroll
            for (int r = 0; r < 4; r++) {
                int rw = qs * 16 + quad * 4 + r;
                float l = Lm[0][rw] + Lm[1][rw] + Lm[2][rw] + Lm[3][rw];
                float inv = 1.0f / l;
                u16* op = attn + (size_t)(q0 + rw) * 768 + h * 64;
#pragma unroll
                for (int nt = 0; nt < 4; nt++) {
                    float v = o[qs][nt][r] + M0[rw * 68 + nt * 16 + l16];
                    op[nt * 16 + l16] = f2bf(v * inv);
                }
            }
        }
    }
}

// ---------------------------------------------------------------------------
extern "C" void kernel_launch(void* const* d_in, const int* in_sizes, int n_in,
                              void* d_out, int out_size, void* d_ws, size_t ws_size,
                              hipStream_t stream) {
    const float* x      = (const float*)d_in[0];  // [4096][768] fp32
    const float* w_qkv  = (const float*)d_in[1];  // [768][2304] fp32
    const float* b_qkv  = (const float*)d_in[2];  // [2304] fp32
    const float* w_o    = (const float*)d_in[3];  // [768][768] fp32
    const float* b_o    = (const float*)d_in[4];  // [768] fp32
    float* out = (float*)d_out;                   // [4096][768] fp32

    u16* wqkvT = (u16*)d_ws;                       // [2304][768] bf16  3.54 MB
    u16* woT   = wqkvT + (size_t)2304 * 768;       // [768][768]  bf16  1.18 MB
    u16* qkv   = woT + (size_t)768 * 768;          // [4096][2304] bf16 18.87 MB
    u16* attnb = qkv + (size_t)4096 * 2304;        // [4096][768] bf16  6.29 MB
    u16* Vt    = attnb + (size_t)4096 * 768;       // [12*64][4096] bf16 6.29 MB
    u16* xb    = attnb;  // aliases attnb: xb dead before attn writes attnb
    // total 36.17 MB == r5/r6 footprint

    transpose_f32_bf16<<<dim3(2304 / 32, 768 / 32), dim3(32, 8), 0, stream>>>(
        w_qkv, wqkvT, 768, 2304);
    transpose_f32_bf16<<<dim3(768 / 32, 768 / 32), dim3(32, 8), 0, stream>>>(
        w_o, woT, 768, 768);
    cvt_f32_bf16<<<dim3(4096 * 768 / (256 * 8)), 256, 0, stream>>>(x, xb);

    gemm_bt<false, true><<<dim3(2304 / 128, 4096 / 128), 256, 0, stream>>>(
        xb, wqkvT, b_qkv, qkv, 4096, 2304, 768);

    vtrans<<<dim3(SEQ / 128, 12), 256, 0, stream>>>(qkv, Vt);

    attn_flash<<<dim3(SEQ / 64, 12), 256, 0, stream>>>(qkv, Vt, attnb);

    gemm_bt<true, false><<<dim3(768 / 128, 4096 / 128), 256, 0, stream>>>(
        attnb, woT, b_o, out, 4096, 768, 768);
}

// Round 8
// 233.175 us; speedup vs baseline: 1.1284x; 1.1284x over previous
//
#include <hip/hip_runtime.h>

typedef unsigned short u16;
typedef __attribute__((ext_vector_type(8))) short bf16x8;   // 8 bf16 in 4 VGPRs
typedef __attribute__((ext_vector_type(4))) float f32x4;

#define CST 0.18033688011112042f  // 0.125 * log2(e)

__device__ inline u16 f2bf(float f) {
    unsigned u;
    __builtin_memcpy(&u, &f, 4);
    unsigned r = (u + 0x7FFF + ((u >> 16) & 1)) >> 16;   // RNE
    return (u16)r;
}
__device__ inline unsigned pack2(float lo, float hi) {
    return (unsigned)f2bf(lo) | ((unsigned)f2bf(hi) << 16);
}
__device__ inline unsigned fbits(float f) {
    unsigned u;
    __builtin_memcpy(&u, &f, 4);
    return u;
}
__device__ inline f32x4 fzero() {
    f32x4 z = {0.f, 0.f, 0.f, 0.f};
    return z;
}
__device__ inline f32x4 mfma16(bf16x8 a, bf16x8 b, f32x4 c) {
    return __builtin_amdgcn_mfma_f32_16x16x32_bf16(a, b, c, 0, 0, 0);
}

// ---------------------------------------------------------------------------
// fp32 -> bf16 tiled transpose: out[C][R] (bf16) = in[R][C] (fp32)
// ---------------------------------------------------------------------------
__global__ void transpose_f32_bf16(const float* __restrict__ in,
                                   u16* __restrict__ out, int R, int C) {
    __shared__ float tile[32][33];
    int c0 = blockIdx.x * 32, r0 = blockIdx.y * 32;
    int tx = threadIdx.x, ty = threadIdx.y;  // 32 x 8
#pragma unroll
    for (int j = 0; j < 32; j += 8)
        tile[ty + j][tx] = in[(size_t)(r0 + ty + j) * C + c0 + tx];
    __syncthreads();
#pragma unroll
    for (int j = 0; j < 32; j += 8)
        out[(size_t)(c0 + ty + j) * R + r0 + tx] = f2bf(tile[tx][ty + j]);
}

// ---------------------------------------------------------------------------
// fp32 -> bf16 flat convert (x). 8 elements/thread.
// ---------------------------------------------------------------------------
__global__ __launch_bounds__(256) void cvt_f32_bf16(const float* __restrict__ in,
                                                    u16* __restrict__ out) {
    int i = (blockIdx.x * 256 + threadIdx.x) * 8;
    float4 a = *(const float4*)(in + i);
    float4 b = *(const float4*)(in + i + 4);
    uint4 w;
    w.x = pack2(a.x, a.y);
    w.y = pack2(a.z, a.w);
    w.z = pack2(b.x, b.y);
    w.w = pack2(b.z, b.w);
    *(uint4*)(out + i) = w;
}

// ---------------------------------------------------------------------------
// V pre-transpose with per-32-key permutation matched to the in-register
// P fragment: within each 32-key group, natural k (= st*16 + quad*4 + r)
// maps to k' = quad*8 + st*4 + r.
// qkv [4096][2304] (V at 1536+h*64+dh) -> vt[h*64+dh][key'].
// ---------------------------------------------------------------------------
__global__ __launch_bounds__(256) void vtrans(const u16* __restrict__ qkv,
                                              u16* __restrict__ vt) {
    __shared__ u16 T[64 * 136];  // [dh][key'] padded
    int t = threadIdx.x;
    int h = blockIdx.y, kv0 = blockIdx.x * 128;
    {
        int key = t >> 1, ch = (t & 1) * 32;
        const u16* vp = qkv + (size_t)(kv0 + key) * 2304 + 1536 + h * 64 + ch;
        u16 tmp[32];
        *(uint4*)&tmp[0]  = *(const uint4*)vp;
        *(uint4*)&tmp[8]  = *(const uint4*)(vp + 8);
        *(uint4*)&tmp[16] = *(const uint4*)(vp + 16);
        *(uint4*)&tmp[24] = *(const uint4*)(vp + 24);
        int k5 = key & 31, grp = key >> 5;
        // k5 = st*16 + q*4 + r  ->  kp = q*8 + st*4 + r
        int kp = (grp << 5) | (((k5 >> 2) & 3) << 3) | ((k5 >> 4) << 2) | (k5 & 3);
#pragma unroll
        for (int j = 0; j < 32; j++) T[(ch + j) * 136 + kp] = tmp[j];
    }
    __syncthreads();
    {
        int dh = t >> 2, kc = (t & 3) * 32;
        uint4 o0 = *(const uint4*)&T[dh * 136 + kc];
        uint4 o1 = *(const uint4*)&T[dh * 136 + kc + 8];
        uint4 o2 = *(const uint4*)&T[dh * 136 + kc + 16];
        uint4 o3 = *(const uint4*)&T[dh * 136 + kc + 24];
        u16* op = vt + ((size_t)(h * 64 + dh)) * 4096 + kv0 + kc;
        *(uint4*)op = o0;
        *(uint4*)(op + 8) = o1;
        *(uint4*)(op + 16) = o2;
        *(uint4*)(op + 24) = o3;
    }
}

// ---------------------------------------------------------------------------
// C[M,N] = A[M,K] @ Bt[N,K]^T + bias[N].  A,Bt bf16; bias fp32; C fp32 or bf16.
// SCALE_Q: multiply by CST for cols < 768.  (validated r4-r7)
// ---------------------------------------------------------------------------
#define GLDA 40  // 32 + 8 pad

template <bool OUT_F32, bool SCALE_Q>
__global__ __launch_bounds__(256) void gemm_bt(const u16* __restrict__ A,
                                               const u16* __restrict__ Bt,
                                               const float* __restrict__ bias,
                                               void* __restrict__ Cv,
                                               int M, int N, int K) {
    __shared__ u16 As[128 * GLDA];
    __shared__ u16 Bs[128 * GLDA];

    int t = threadIdx.x;
    int wave = t >> 6, lane = t & 63, quad = lane >> 4, l16 = lane & 15;
    int mbase = blockIdx.y * 128, nbase = blockIdx.x * 128;
    int mw = (wave & 1) * 64, nw = (wave >> 1) * 64;

    f32x4 acc[4][4];
#pragma unroll
    for (int i = 0; i < 4; i++)
#pragma unroll
        for (int j = 0; j < 4; j++) acc[i][j] = fzero();

    int arow = t >> 1, acol = (t & 1) * 16;
    const u16* Ag = A + (size_t)(mbase + arow) * K + acol;
    const u16* Bg = Bt + (size_t)(nbase + arow) * K + acol;
    u16* Asw = &As[arow * GLDA + acol];
    u16* Bsw = &Bs[arow * GLDA + acol];

    for (int kt = 0; kt < K; kt += 32) {
        uint4 a0 = *(const uint4*)(Ag + kt);
        uint4 a1 = *(const uint4*)(Ag + kt + 8);
        uint4 b0 = *(const uint4*)(Bg + kt);
        uint4 b1 = *(const uint4*)(Bg + kt + 8);
        *(uint4*)(Asw) = a0;
        *(uint4*)(Asw + 8) = a1;
        *(uint4*)(Bsw) = b0;
        *(uint4*)(Bsw + 8) = b1;
        __syncthreads();

        bf16x8 af[4], bfr[4];
#pragma unroll
        for (int i = 0; i < 4; i++)
            af[i] = *(const bf16x8*)&As[(mw + i * 16 + l16) * GLDA + quad * 8];
#pragma unroll
        for (int i = 0; i < 4; i++)
            bfr[i] = *(const bf16x8*)&Bs[(nw + i * 16 + l16) * GLDA + quad * 8];
#pragma unroll
        for (int mi = 0; mi < 4; mi++)
#pragma unroll
            for (int ni = 0; ni < 4; ni++)
                acc[mi][ni] = mfma16(af[mi], bfr[ni], acc[mi][ni]);
        __syncthreads();
    }

#pragma unroll
    for (int ni = 0; ni < 4; ni++) {
        int col = nbase + nw + ni * 16 + l16;
        float bv = bias[col];
        float scale = (SCALE_Q && col < 768) ? CST : 1.0f;
#pragma unroll
        for (int mi = 0; mi < 4; mi++) {
#pragma unroll
            for (int r = 0; r < 4; r++) {
                int row = mbase + mw + mi * 16 + quad * 4 + r;
                float v = (acc[mi][ni][r] + bv) * scale;
                if (OUT_F32)
                    ((float*)Cv)[(size_t)row * N + col] = v;
                else
                    ((u16*)Cv)[(size_t)row * N + col] = f2bf(v);
            }
        }
    }
}

// ---------------------------------------------------------------------------
// MFMA flash attention v4: key-split waves + in-register P.
// S^T = K·Q^T so each lane's C-layout output IS the PV A-operand under the
// key permutation k' = quad*8 + st*4 + r (V pre-permuted to match).
// Block = 4 waves, 64 q-rows, KV tiles of 128; wave w owns keys w*32..+32.
// Max-free softmax (Q pre-scaled by CST), exact cross-wave merge at end.
// ---------------------------------------------------------------------------
#define SEQ 4096
#define QKV_LD 2304
#define LK 72    // Ks row stride (64 + 8)
#define LV 136   // VTs row stride (128 + 8)

__global__ __launch_bounds__(256, 3) void attn_flash(const u16* __restrict__ qkv,
                                                     const u16* __restrict__ vt,
                                                     u16* __restrict__ attn) {
    // Ks [128][LK] u16 (18432 B) | VTs [64][LV] u16 (17408 B) = 35840 B
    // epilogue reuses the same space as M0/M1 [64][68] fp32 (17408 B each)
    __shared__ __align__(16) char smem[35840];
    u16* Ks  = (u16*)smem;
    u16* VTs = (u16*)(smem + 18432);
    __shared__ float Lm[4][64];

    int t = threadIdx.x;
    int wave = t >> 6, lane = t & 63, quad = lane >> 4, l16 = lane & 15;
    int h = blockIdx.y;
    int q0 = blockIdx.x * 64;
    const int QOFF = h * 64, KOFF = 768 + h * 64;

    // Q fragments (B-operand of S^T = K·Q^T; same loads as A-layout of Q)
    bf16x8 qf[4][2];
#pragma unroll
    for (int qs = 0; qs < 4; qs++) {
        const u16* qp = qkv + (size_t)(q0 + qs * 16 + l16) * QKV_LD + QOFF + quad * 8;
        qf[qs][0] = *(const bf16x8*)(qp);
        qf[qs][1] = *(const bf16x8*)(qp + 32);
    }

    f32x4 o[4][4];
    float l4[4];
#pragma unroll
    for (int qs = 0; qs < 4; qs++) {
        l4[qs] = 0.f;
#pragma unroll
        for (int j = 0; j < 4; j++) o[qs][j] = fzero();
    }

    // staging coords
    int krow = t >> 1, kch = (t & 1) * 32;    // K: 128 rows x 64 dh
    int vdh = t >> 2, vkc = (t & 3) * 32;     // V^T: 64 rows x 128 keys'
    const u16* kg = qkv + (size_t)krow * QKV_LD + KOFF + kch;
    const u16* vg = vt + ((size_t)(h * 64 + vdh)) * SEQ + vkc;
    u16* kd = &Ks[krow * LK + kch];
    u16* vd = &VTs[vdh * LV + vkc];

    for (int kv0 = 0; kv0 < SEQ; kv0 += 128) {
        // ---- stage K [128][64] and V^T [64][128'] — all b128 ----
        {
            const u16* kp = kg + (size_t)kv0 * QKV_LD;
            uint4 k0 = *(const uint4*)kp;
            uint4 k1 = *(const uint4*)(kp + 8);
            uint4 k2 = *(const uint4*)(kp + 16);
            uint4 k3 = *(const uint4*)(kp + 24);
            *(uint4*)kd = k0;
            *(uint4*)(kd + 8) = k1;
            *(uint4*)(kd + 16) = k2;
            *(uint4*)(kd + 24) = k3;
            const u16* vp = vg + kv0;
            uint4 v0 = *(const uint4*)vp;
            uint4 v1 = *(const uint4*)(vp + 8);
            uint4 v2 = *(const uint4*)(vp + 16);
            uint4 v3 = *(const uint4*)(vp + 24);
            *(uint4*)vd = v0;
            *(uint4*)(vd + 8) = v1;
            *(uint4*)(vd + 16) = v2;
            *(uint4*)(vd + 24) = v3;
        }
        __syncthreads();

        // ---- K fragments (A-operand) for this wave's 32 keys ----
        bf16x8 kf[2][2];
#pragma unroll
        for (int st = 0; st < 2; st++) {
            const u16* kb = &Ks[(wave * 32 + st * 16 + l16) * LK + quad * 8];
            kf[st][0] = *(const bf16x8*)(kb);
            kf[st][1] = *(const bf16x8*)(kb + 32);
        }
        // ---- V fragments (B-operand rows of V^T) ----
        bf16x8 vf[4];
#pragma unroll
        for (int nt = 0; nt < 4; nt++)
            vf[nt] = *(const bf16x8*)&VTs[(nt * 16 + l16) * LV + wave * 32 + quad * 8];

        // ---- per q-subtile: S^T, exp2, in-register P, PV ----
#pragma unroll
        for (int qs = 0; qs < 4; qs++) {
            f32x4 s0 = mfma16(kf[0][0], qf[qs][0], fzero());
            s0 = mfma16(kf[0][1], qf[qs][1], s0);
            f32x4 s1 = mfma16(kf[1][0], qf[qs][0], fzero());
            s1 = mfma16(kf[1][1], qf[qs][1], s1);
            float p00 = exp2f(s0[0]), p01 = exp2f(s0[1]);
            float p02 = exp2f(s0[2]), p03 = exp2f(s0[3]);
            float p10 = exp2f(s1[0]), p11 = exp2f(s1[1]);
            float p12 = exp2f(s1[2]), p13 = exp2f(s1[3]);
            l4[qs] += ((p00 + p01) + (p02 + p03)) + ((p10 + p11) + (p12 + p13));
            uint4 pk;
            pk.x = __builtin_amdgcn_perm(fbits(p01), fbits(p00), 0x07060302u);
            pk.y = __builtin_amdgcn_perm(fbits(p03), fbits(p02), 0x07060302u);
            pk.z = __builtin_amdgcn_perm(fbits(p11), fbits(p10), 0x07060302u);
            pk.w = __builtin_amdgcn_perm(fbits(p13), fbits(p12), 0x07060302u);
            bf16x8 pf;
            __builtin_memcpy(&pf, &pk, 16);
#pragma unroll
            for (int nt = 0; nt < 4; nt++)
                o[qs][nt] = mfma16(pf, vf[nt], o[qs][nt]);
        }
        __syncthreads();
    }

    // ---- l: sum across the 4 quads holding q-row l16 ----
#pragma unroll
    for (int qs = 0; qs < 4; qs++) {
        l4[qs] += __shfl_xor(l4[qs], 16);
        l4[qs] += __shfl_xor(l4[qs], 32);
    }
    if (lane < 16) {
#pragma unroll
        for (int qs = 0; qs < 4; qs++) Lm[wave][qs * 16 + l16] = l4[qs];
    }

    // ---- cross-wave O merge (exact: max-free partials just add) ----
    float* M0 = (float*)smem;              // [64][68]
    float* M1 = (float*)(smem + 17408);    // [64][68]
    __syncthreads();
    if (wave >= 2) {
        float* M = (wave == 2) ? M0 : M1;
#pragma unroll
        for (int qs = 0; qs < 4; qs++)
#pragma unroll
            for (int nt = 0; nt < 4; nt++)
#pragma unroll
                for (int r = 0; r < 4; r++)
                    M[(qs * 16 + quad * 4 + r) * 68 + nt * 16 + l16] = o[qs][nt][r];
    }
    __syncthreads();
    if (wave < 2) {
        float* M = (wave == 0) ? M0 : M1;
#pragma unroll
        for (int qs = 0; qs < 4; qs++)
#pragma unroll
            for (int nt = 0; nt < 4; nt++)
#pragma unroll
                for (int r = 0; r < 4; r++)
                    o[qs][nt][r] += M[(qs * 16 + quad * 4 + r) * 68 + nt * 16 + l16];
    }
    __syncthreads();
    if (wave == 1) {
#pragma unroll
        for (int qs = 0; qs < 4; qs++)
#pragma unroll
            for (int nt = 0; nt < 4; nt++)
#pragma unroll
                for (int r = 0; r < 4; r++)
                    M0[(qs * 16 + quad * 4 + r) * 68 + nt * 16 + l16] = o[qs][nt][r];
    }
    __syncthreads();
    if (wave == 0) {
#pragma unroll
        for (int qs = 0; qs < 4; qs++) {
#pragma unroll
            for (int r = 0; r < 4; r++) {
                int rw = qs * 16 + quad * 4 + r;
                float l = Lm[0][rw] + Lm[1][rw] + Lm[2][rw] + Lm[3][rw];
                float inv = 1.0f / l;
                u16* op = attn + (size_t)(q0 + rw) * 768 + h * 64;
#pragma unroll
                for (int nt = 0; nt < 4; nt++) {
                    float v = o[qs][nt][r] + M0[rw * 68 + nt * 16 + l16];
                    op[nt * 16 + l16] = f2bf(v * inv);
                }
            }
        }
    }
}

// ---------------------------------------------------------------------------
extern "C" void kernel_launch(void* const* d_in, const int* in_sizes, int n_in,
                              void* d_out, int out_size, void* d_ws, size_t ws_size,
                              hipStream_t stream) {
    const float* x      = (const float*)d_in[0];  // [4096][768] fp32
    const float* w_qkv  = (const float*)d_in[1];  // [768][2304] fp32
    const float* b_qkv  = (const float*)d_in[2];  // [2304] fp32
    const float* w_o    = (const float*)d_in[3];  // [768][768] fp32
    const float* b_o    = (const float*)d_in[4];  // [768] fp32
    float* out = (float*)d_out;                   // [4096][768] fp32

    u16* wqkvT = (u16*)d_ws;                       // [2304][768] bf16  3.54 MB
    u16* woT   = wqkvT + (size_t)2304 * 768;       // [768][768]  bf16  1.18 MB
    u16* qkv   = woT + (size_t)768 * 768;          // [4096][2304] bf16 18.87 MB
    u16* attnb = qkv + (size_t)4096 * 2304;        // [4096][768] bf16  6.29 MB
    u16* Vt    = attnb + (size_t)4096 * 768;       // [12*64][4096] bf16 6.29 MB
    u16* xb    = attnb;  // aliases attnb: xb dead before attn writes attnb
    // total 36.17 MB == r5-r7 footprint

    transpose_f32_bf16<<<dim3(2304 / 32, 768 / 32), dim3(32, 8), 0, stream>>>(
        w_qkv, wqkvT, 768, 2304);
    transpose_f32_bf16<<<dim3(768 / 32, 768 / 32), dim3(32, 8), 0, stream>>>(
        w_o, woT, 768, 768);
    cvt_f32_bf16<<<dim3(4096 * 768 / (256 * 8)), 256, 0, stream>>>(x, xb);

    gemm_bt<false, true><<<dim3(2304 / 128, 4096 / 128), 256, 0, stream>>>(
        xb, wqkvT, b_qkv, qkv, 4096, 2304, 768);

    vtrans<<<dim3(SEQ / 128, 12), 256, 0, stream>>>(qkv, Vt);

    attn_flash<<<dim3(SEQ / 64, 12), 256, 0, stream>>>(qkv, Vt, attnb);

    gemm_bt<true, false><<<dim3(768 / 128, 4096 / 128), 256, 0, stream>>>(
        attnb, woT, b_o, out, 4096, 768, 768);
}

// Round 9
// 218.422 us; speedup vs baseline: 1.2046x; 1.0675x over previous
//
#include <hip/hip_runtime.h>

typedef unsigned short u16;
typedef __attribute__((ext_vector_type(8))) short bf16x8;   // 8 bf16 in 4 VGPRs
typedef __attribute__((ext_vector_type(4))) float f32x4;

#define CST 0.18033688011112042f  // 0.125 * log2(e)

__device__ inline u16 f2bf(float f) {
    unsigned u;
    __builtin_memcpy(&u, &f, 4);
    unsigned r = (u + 0x7FFF + ((u >> 16) & 1)) >> 16;   // RNE
    return (u16)r;
}
__device__ inline unsigned pack2(float lo, float hi) {
    return (unsigned)f2bf(lo) | ((unsigned)f2bf(hi) << 16);
}
__device__ inline unsigned fbits(float f) {
    unsigned u;
    __builtin_memcpy(&u, &f, 4);
    return u;
}
__device__ inline f32x4 fzero() {
    f32x4 z = {0.f, 0.f, 0.f, 0.f};
    return z;
}
__device__ inline f32x4 mfma16(bf16x8 a, bf16x8 b, f32x4 c) {
    return __builtin_amdgcn_mfma_f32_16x16x32_bf16(a, b, c, 0, 0, 0);
}

// async global->LDS, 16B per lane; lds dst = wave-uniform base + lane*16
__device__ inline void gld_lds16(const u16* g, u16* l) {
    __builtin_amdgcn_global_load_lds(
        reinterpret_cast<const __attribute__((address_space(1))) unsigned int*>(
            reinterpret_cast<uintptr_t>(g)),
        reinterpret_cast<__attribute__((address_space(3))) unsigned int*>(
            static_cast<unsigned int>(reinterpret_cast<uintptr_t>(l))),
        16, 0, 0);
}

// ---------------------------------------------------------------------------
// prep: fused  (a) w_qkv transpose fp32->bf16  (b) w_o transpose
//              (c) x fp32->bf16 flat convert
// ---------------------------------------------------------------------------
#define NB_WQKV (72 * 24)   // 2304/32 x 768/32
#define NB_WO   (24 * 24)
#define NB_CVT  (4096 * 768 / 2048)

__global__ __launch_bounds__(256) void prep(const float* __restrict__ x,
                                            const float* __restrict__ w_qkv,
                                            const float* __restrict__ w_o,
                                            u16* __restrict__ xb,
                                            u16* __restrict__ wqkvT,
                                            u16* __restrict__ woT) {
    __shared__ float tile[32][33];
    int bid = blockIdx.x;
    int t = threadIdx.x;
    if (bid < NB_WQKV + NB_WO) {
        const float* in;
        u16* out;
        int bx, by, R, C;
        if (bid < NB_WQKV) {
            in = w_qkv; out = wqkvT; R = 768; C = 2304;
            bx = bid % 72; by = bid / 72;
        } else {
            int b2 = bid - NB_WQKV;
            in = w_o; out = woT; R = 768; C = 768;
            bx = b2 % 24; by = b2 / 24;
        }
        int c0 = bx * 32, r0 = by * 32;
        int tx = t & 31, ty = t >> 5;  // 32 x 8
#pragma unroll
        for (int j = 0; j < 32; j += 8)
            tile[ty + j][tx] = in[(size_t)(r0 + ty + j) * C + c0 + tx];
        __syncthreads();
#pragma unroll
        for (int j = 0; j < 32; j += 8)
            out[(size_t)(c0 + ty + j) * R + r0 + tx] = f2bf(tile[tx][ty + j]);
    } else {
        int i = (bid - NB_WQKV - NB_WO) * 2048 + t * 8;
        float4 a = *(const float4*)(x + i);
        float4 b = *(const float4*)(x + i + 4);
        uint4 w;
        w.x = pack2(a.x, a.y);
        w.y = pack2(a.z, a.w);
        w.z = pack2(b.x, b.y);
        w.w = pack2(b.z, b.w);
        *(uint4*)(xb + i) = w;
    }
}

// ---------------------------------------------------------------------------
// V pre-transpose with per-32-key permutation matched to the in-register
// P fragment: within each 32-key group, natural k (= st*16 + quad*4 + r)
// maps to k' = quad*8 + st*4 + r.   (validated r8)
// ---------------------------------------------------------------------------
__global__ __launch_bounds__(256) void vtrans(const u16* __restrict__ qkv,
                                              u16* __restrict__ vt) {
    __shared__ u16 T[64 * 136];  // [dh][key'] padded
    int t = threadIdx.x;
    int h = blockIdx.y, kv0 = blockIdx.x * 128;
    {
        int key = t >> 1, ch = (t & 1) * 32;
        const u16* vp = qkv + (size_t)(kv0 + key) * 2304 + 1536 + h * 64 + ch;
        u16 tmp[32];
        *(uint4*)&tmp[0]  = *(const uint4*)vp;
        *(uint4*)&tmp[8]  = *(const uint4*)(vp + 8);
        *(uint4*)&tmp[16] = *(const uint4*)(vp + 16);
        *(uint4*)&tmp[24] = *(const uint4*)(vp + 24);
        int k5 = key & 31, grp = key >> 5;
        int kp = (grp << 5) | (((k5 >> 2) & 3) << 3) | ((k5 >> 4) << 2) | (k5 & 3);
#pragma unroll
        for (int j = 0; j < 32; j++) T[(ch + j) * 136 + kp] = tmp[j];
    }
    __syncthreads();
    {
        int dh = t >> 2, kc = (t & 3) * 32;
        uint4 o0 = *(const uint4*)&T[dh * 136 + kc];
        uint4 o1 = *(const uint4*)&T[dh * 136 + kc + 8];
        uint4 o2 = *(const uint4*)&T[dh * 136 + kc + 16];
        uint4 o3 = *(const uint4*)&T[dh * 136 + kc + 24];
        u16* op = vt + ((size_t)(h * 64 + dh)) * 4096 + kv0 + kc;
        *(uint4*)op = o0;
        *(uint4*)(op + 8) = o1;
        *(uint4*)(op + 16) = o2;
        *(uint4*)(op + 24) = o3;
    }
}

// ---------------------------------------------------------------------------
// C[M,N] = A[M,K] @ Bt[N,K]^T + bias[N].  A,Bt bf16; bias fp32; C f32/bf16.
// MT x 128 tile, BK=32, 4 waves, 16x16x32 MFMA.
// Staging via global_load_lds(16B) into XOR-swizzled LDS:
//   chunk(row, qc) at byte row*64 + (qc ^ ((row>>1)&3))*16
//   staging lane L -> row = wrow0 + j*16 + L/4, qc = (L&3)^((L>>3)&3)
//   fragment read offset: row*32 + (quad^((l16>>1)&3))*8 elements
// ---------------------------------------------------------------------------
template <int MT, bool OUT_F32, bool SCALE_Q>
__global__ __launch_bounds__(256) void gemm_bt(const u16* __restrict__ A,
                                               const u16* __restrict__ Bt,
                                               const float* __restrict__ bias,
                                               void* __restrict__ Cv,
                                               int M, int N, int K) {
    constexpr int MI = MT / 32;   // per-wave m-tiles (4 or 2)
    constexpr int NA = MT / 64;   // A staging insts per wave (2 or 1)
    __shared__ u16 As[MT * 32];
    __shared__ u16 Bs[128 * 32];

    int t = threadIdx.x;
    int wave = t >> 6, lane = t & 63, quad = lane >> 4, l16 = lane & 15;
    int mbase = blockIdx.y * MT, nbase = blockIdx.x * 128;
    int mw = (wave & 1) * (MT / 2), nw = (wave >> 1) * 64;

    f32x4 acc[MI][4];
#pragma unroll
    for (int i = 0; i < MI; i++)
#pragma unroll
        for (int j = 0; j < 4; j++) acc[i][j] = fzero();

    // staging pointers (loop-invariant; +kt each iteration)
    int xqs = (lane & 3) ^ ((lane >> 3) & 3);
    const u16* AgL[NA];
    u16* AsL[NA];
#pragma unroll
    for (int j = 0; j < NA; j++) {
        int rl = wave * (MT / 4) + j * 16 + (lane >> 2);
        AgL[j] = A + (size_t)(mbase + rl) * K + xqs * 8;
        AsL[j] = As + wave * (MT / 4) * 32 + j * 512;  // wave-uniform
    }
    const u16* BgL[2];
    u16* BsL[2];
#pragma unroll
    for (int j = 0; j < 2; j++) {
        int rl = wave * 32 + j * 16 + (lane >> 2);
        BgL[j] = Bt + (size_t)(nbase + rl) * K + xqs * 8;
        BsL[j] = Bs + wave * 1024 + j * 512;
    }

    // fragment read offsets (loop-invariant)
    int xq = quad ^ ((l16 >> 1) & 3);
    int afo[MI], bfo[4];
#pragma unroll
    for (int i = 0; i < MI; i++) afo[i] = (mw + i * 16 + l16) * 32 + xq * 8;
#pragma unroll
    for (int i = 0; i < 4; i++) bfo[i] = (nw + i * 16 + l16) * 32 + xq * 8;

    for (int kt = 0; kt < K; kt += 32) {
#pragma unroll
        for (int j = 0; j < NA; j++) gld_lds16(AgL[j] + kt, AsL[j]);
#pragma unroll
        for (int j = 0; j < 2; j++) gld_lds16(BgL[j] + kt, BsL[j]);
        __syncthreads();

        bf16x8 af[MI], bfr[4];
#pragma unroll
        for (int i = 0; i < MI; i++) af[i] = *(const bf16x8*)&As[afo[i]];
#pragma unroll
        for (int i = 0; i < 4; i++) bfr[i] = *(const bf16x8*)&Bs[bfo[i]];
#pragma unroll
        for (int mi = 0; mi < MI; mi++)
#pragma unroll
            for (int ni = 0; ni < 4; ni++)
                acc[mi][ni] = mfma16(af[mi], bfr[ni], acc[mi][ni]);
        __syncthreads();
    }

#pragma unroll
    for (int ni = 0; ni < 4; ni++) {
        int col = nbase + nw + ni * 16 + l16;
        float bv = bias[col];
        float scale = (SCALE_Q && col < 768) ? CST : 1.0f;
#pragma unroll
        for (int mi = 0; mi < MI; mi++) {
#pragma unroll
            for (int r = 0; r < 4; r++) {
                int row = mbase + mw + mi * 16 + quad * 4 + r;
                float v = (acc[mi][ni][r] + bv) * scale;
                if (OUT_F32)
                    ((float*)Cv)[(size_t)row * N + col] = v;
                else
                    ((u16*)Cv)[(size_t)row * N + col] = f2bf(v);
            }
        }
    }
}

// ---------------------------------------------------------------------------
// MFMA flash attention v4 (byte-identical to r8): key-split waves +
// in-register P via S^T = K·Q^T and matched V permutation.
// ---------------------------------------------------------------------------
#define SEQ 4096
#define QKV_LD 2304
#define LK 72    // Ks row stride (64 + 8)
#define LV 136   // VTs row stride (128 + 8)

__global__ __launch_bounds__(256, 3) void attn_flash(const u16* __restrict__ qkv,
                                                     const u16* __restrict__ vt,
                                                     u16* __restrict__ attn) {
    __shared__ __align__(16) char smem[35840];
    u16* Ks  = (u16*)smem;
    u16* VTs = (u16*)(smem + 18432);
    __shared__ float Lm[4][64];

    int t = threadIdx.x;
    int wave = t >> 6, lane = t & 63, quad = lane >> 4, l16 = lane & 15;
    int h = blockIdx.y;
    int q0 = blockIdx.x * 64;
    const int QOFF = h * 64, KOFF = 768 + h * 64;

    bf16x8 qf[4][2];
#pragma unroll
    for (int qs = 0; qs < 4; qs++) {
        const u16* qp = qkv + (size_t)(q0 + qs * 16 + l16) * QKV_LD + QOFF + quad * 8;
        qf[qs][0] = *(const bf16x8*)(qp);
        qf[qs][1] = *(const bf16x8*)(qp + 32);
    }

    f32x4 o[4][4];
    float l4[4];
#pragma unroll
    for (int qs = 0; qs < 4; qs++) {
        l4[qs] = 0.f;
#pragma unroll
        for (int j = 0; j < 4; j++) o[qs][j] = fzero();
    }

    int krow = t >> 1, kch = (t & 1) * 32;
    int vdh = t >> 2, vkc = (t & 3) * 32;
    const u16* kg = qkv + (size_t)krow * QKV_LD + KOFF + kch;
    const u16* vg = vt + ((size_t)(h * 64 + vdh)) * SEQ + vkc;
    u16* kd = &Ks[krow * LK + kch];
    u16* vd = &VTs[vdh * LV + vkc];

    for (int kv0 = 0; kv0 < SEQ; kv0 += 128) {
        {
            const u16* kp = kg + (size_t)kv0 * QKV_LD;
            uint4 k0 = *(const uint4*)kp;
            uint4 k1 = *(const uint4*)(kp + 8);
            uint4 k2 = *(const uint4*)(kp + 16);
            uint4 k3 = *(const uint4*)(kp + 24);
            *(uint4*)kd = k0;
            *(uint4*)(kd + 8) = k1;
            *(uint4*)(kd + 16) = k2;
            *(uint4*)(kd + 24) = k3;
            const u16* vp = vg + kv0;
            uint4 v0 = *(const uint4*)vp;
            uint4 v1 = *(const uint4*)(vp + 8);
            uint4 v2 = *(const uint4*)(vp + 16);
            uint4 v3 = *(const uint4*)(vp + 24);
            *(uint4*)vd = v0;
            *(uint4*)(vd + 8) = v1;
            *(uint4*)(vd + 16) = v2;
            *(uint4*)(vd + 24) = v3;
        }
        __syncthreads();

        bf16x8 kf[2][2];
#pragma unroll
        for (int st = 0; st < 2; st++) {
            const u16* kb = &Ks[(wave * 32 + st * 16 + l16) * LK + quad * 8];
            kf[st][0] = *(const bf16x8*)(kb);
            kf[st][1] = *(const bf16x8*)(kb + 32);
        }
        bf16x8 vf[4];
#pragma unroll
        for (int nt = 0; nt < 4; nt++)
            vf[nt] = *(const bf16x8*)&VTs[(nt * 16 + l16) * LV + wave * 32 + quad * 8];

#pragma unroll
        for (int qs = 0; qs < 4; qs++) {
            f32x4 s0 = mfma16(kf[0][0], qf[qs][0], fzero());
            s0 = mfma16(kf[0][1], qf[qs][1], s0);
            f32x4 s1 = mfma16(kf[1][0], qf[qs][0], fzero());
            s1 = mfma16(kf[1][1], qf[qs][1], s1);
            float p00 = exp2f(s0[0]), p01 = exp2f(s0[1]);
            float p02 = exp2f(s0[2]), p03 = exp2f(s0[3]);
            float p10 = exp2f(s1[0]), p11 = exp2f(s1[1]);
            float p12 = exp2f(s1[2]), p13 = exp2f(s1[3]);
            l4[qs] += ((p00 + p01) + (p02 + p03)) + ((p10 + p11) + (p12 + p13));
            uint4 pk;
            pk.x = __builtin_amdgcn_perm(fbits(p01), fbits(p00), 0x07060302u);
            pk.y = __builtin_amdgcn_perm(fbits(p03), fbits(p02), 0x07060302u);
            pk.z = __builtin_amdgcn_perm(fbits(p11), fbits(p10), 0x07060302u);
            pk.w = __builtin_amdgcn_perm(fbits(p13), fbits(p12), 0x07060302u);
            bf16x8 pf;
            __builtin_memcpy(&pf, &pk, 16);
#pragma unroll
            for (int nt = 0; nt < 4; nt++)
                o[qs][nt] = mfma16(pf, vf[nt], o[qs][nt]);
        }
        __syncthreads();
    }

#pragma unroll
    for (int qs = 0; qs < 4; qs++) {
        l4[qs] += __shfl_xor(l4[qs], 16);
        l4[qs] += __shfl_xor(l4[qs], 32);
    }
    if (lane < 16) {
#pragma unroll
        for (int qs = 0; qs < 4; qs++) Lm[wave][qs * 16 + l16] = l4[qs];
    }

    float* M0 = (float*)smem;              // [64][68]
    float* M1 = (float*)(smem + 17408);    // [64][68]
    __syncthreads();
    if (wave >= 2) {
        float* M = (wave == 2) ? M0 : M1;
#pragma unroll
        for (int qs = 0; qs < 4; qs++)
#pragma unroll
            for (int nt = 0; nt < 4; nt++)
#pragma unroll
                for (int r = 0; r < 4; r++)
                    M[(qs * 16 + quad * 4 + r) * 68 + nt * 16 + l16] = o[qs][nt][r];
    }
    __syncthreads();
    if (wave < 2) {
        float* M = (wave == 0) ? M0 : M1;
#pragma unroll
        for (int qs = 0; qs < 4; qs++)
#pragma unroll
            for (int nt = 0; nt < 4; nt++)
#pragma unroll
                for (int r = 0; r < 4; r++)
                    o[qs][nt][r] += M[(qs * 16 + quad * 4 + r) * 68 + nt * 16 + l16];
    }
    __syncthreads();
    if (wave == 1) {
#pragma unroll
        for (int qs = 0; qs < 4; qs++)
#pragma unroll
            for (int nt = 0; nt < 4; nt++)
#pragma unroll
                for (int r = 0; r < 4; r++)
                    M0[(qs * 16 + quad * 4 + r) * 68 + nt * 16 + l16] = o[qs][nt][r];
    }
    __syncthreads();
    if (wave == 0) {
#pragma unroll
        for (int qs = 0; qs < 4; qs++) {
#pragma unroll
            for (int r = 0; r < 4; r++) {
                int rw = qs * 16 + quad * 4 + r;
                float l = Lm[0][rw] + Lm[1][rw] + Lm[2][rw] + Lm[3][rw];
                float inv = 1.0f / l;
                u16* op = attn + (size_t)(q0 + rw) * 768 + h * 64;
#pragma unroll
                for (int nt = 0; nt < 4; nt++) {
                    float v = o[qs][nt][r] + M0[rw * 68 + nt * 16 + l16];
                    op[nt * 16 + l16] = f2bf(v * inv);
                }
            }
        }
    }
}

// ---------------------------------------------------------------------------
extern "C" void kernel_launch(void* const* d_in, const int* in_sizes, int n_in,
                              void* d_out, int out_size, void* d_ws, size_t ws_size,
                              hipStream_t stream) {
    const float* x      = (const float*)d_in[0];  // [4096][768] fp32
    const float* w_qkv  = (const float*)d_in[1];  // [768][2304] fp32
    const float* b_qkv  = (const float*)d_in[2];  // [2304] fp32
    const float* w_o    = (const float*)d_in[3];  // [768][768] fp32
    const float* b_o    = (const float*)d_in[4];  // [768] fp32
    float* out = (float*)d_out;                   // [4096][768] fp32

    u16* wqkvT = (u16*)d_ws;                       // [2304][768] bf16  3.54 MB
    u16* woT   = wqkvT + (size_t)2304 * 768;       // [768][768]  bf16  1.18 MB
    u16* qkv   = woT + (size_t)768 * 768;          // [4096][2304] bf16 18.87 MB
    u16* attnb = qkv + (size_t)4096 * 2304;        // [4096][768] bf16  6.29 MB
    u16* Vt    = attnb + (size_t)4096 * 768;       // [12*64][4096] bf16 6.29 MB
    u16* xb    = attnb;  // aliases attnb: xb dead before attn writes attnb
    // total 36.17 MB == r5-r8 footprint

    prep<<<dim3(NB_WQKV + NB_WO + NB_CVT), 256, 0, stream>>>(
        x, w_qkv, w_o, xb, wqkvT, woT);

    gemm_bt<128, false, true><<<dim3(2304 / 128, 4096 / 128), 256, 0, stream>>>(
        xb, wqkvT, b_qkv, qkv, 4096, 2304, 768);

    vtrans<<<dim3(SEQ / 128, 12), 256, 0, stream>>>(qkv, Vt);

    attn_flash<<<dim3(SEQ / 64, 12), 256, 0, stream>>>(qkv, Vt, attnb);

    gemm_bt<64, true, false><<<dim3(768 / 128, 4096 / 64), 256, 0, stream>>>(
        attnb, woT, b_o, out, 4096, 768, 768);
}